// Round 6
// baseline (765.209 us; speedup 1.0000x reference)
//
#include <hip/hip_runtime.h>
#include <hip/hip_cooperative_groups.h>
#include <stdint.h>

#define B_     64
#define H_     16384
#define NB_    512
#define NNZ_   26214
#define N_IN_  1024
#define N_OUT_ 1024

typedef __attribute__((ext_vector_type(8))) short    bf16x8;
typedef __attribute__((ext_vector_type(4))) float    f32x4;
typedef __attribute__((ext_vector_type(4))) unsigned int u32x4;

__device__ __forceinline__ unsigned short f2bf(float f) {
    union { unsigned int i; float f; } v; v.f = f;
    unsigned int x = v.i;
    return (unsigned short)((x + 0x7fffu + ((x >> 16) & 1u)) >> 16);
}

__device__ __forceinline__ bf16x8 ldfrag(const unsigned short* p) {
    union { u32x4 u; bf16x8 b; } cv;
    cv.u = *(const u32x4*)p;     // 16B aligned by construction
    return cv.b;
}

// ---------------- single-WG index build: hist + scan + scatter --------------
// Replaces 4 tiny dispatches. 1024 threads, everything in LDS.
// Also zeroes the grid-barrier slots used by the persistent kernel.

__global__ __launch_bounds__(1024) void index_k(
        const int* __restrict__ rows, const int* __restrict__ cols,
        int* __restrict__ rowptr, int2* __restrict__ pair2,
        int* __restrict__ bar) {
    __shared__ int s_cnt[NB_];
    __shared__ int s_off[NB_];
    const int t = threadIdx.x;

    if (t < NB_) s_cnt[t] = 0;
    if (t < 64) bar[t] = 0;                      // barrier counter + sense
    __syncthreads();

    for (int n = t; n < NNZ_; n += 1024)
        atomicAdd(&s_cnt[rows[n]], 1);
    __syncthreads();

    // inclusive Hillis-Steele scan over NB_ entries (all threads hit barriers)
    for (int off = 1; off < NB_; off <<= 1) {
        int v = 0;
        if (t < NB_ && t >= off) v = s_cnt[t - off];
        __syncthreads();
        if (t < NB_) s_cnt[t] += v;
        __syncthreads();
    }

    if (t == 0) rowptr[0] = 0;
    if (t < NB_) {
        rowptr[t + 1] = s_cnt[t];
        s_off[t] = (t == 0) ? 0 : s_cnt[t - 1];  // exclusive start per row
    }
    __syncthreads();

    for (int n = t; n < NNZ_; n += 1024) {
        int r = rows[n];
        int pos = atomicAdd(&s_off[r], 1);
        pair2[pos] = make_int2(n, cols[n]);
    }
}

// ---------------- merged prep: weights f32->bf16 (permuted) + init_x --------
// blockIdx < NNZ: wbf[pos] = bf16(blocks[pair2[pos].x])  (one block per WG)
// blockIdx >= NNZ: blocked x[c][b][j] bf16 init from inp (zero-padded)

__global__ __launch_bounds__(256) void prep_k(
        const float* __restrict__ w, unsigned short* __restrict__ wb,
        const int2* __restrict__ pair2,
        const float* __restrict__ inp, unsigned short* __restrict__ xb) {
    const int bb = blockIdx.x;
    if (bb < NNZ_) {
        int t = threadIdx.x;                     // one float4 per thread
        int n = pair2[bb].x;
        f32x4 v = __builtin_nontemporal_load((const f32x4*)(w + (size_t)n * 1024) + t);
        union { unsigned short s[4]; uint2 d; } o;
        o.s[0] = f2bf(v[0]); o.s[1] = f2bf(v[1]);
        o.s[2] = f2bf(v[2]); o.s[3] = f2bf(v[3]);
        ((uint2*)(wb + (size_t)bb * 1024))[t] = o.d;
    } else {
        int idx = (bb - NNZ_) * 256 + threadIdx.x;   // 0 .. B*H-1 blocked linear
        int c = idx >> 11;
        int b = (idx >> 5) & 63;
        int j = idx & 31;
        int h = c * 32 + j;
        xb[idx] = (h < N_IN_) ? f2bf(inp[b * N_IN_ + h]) : (unsigned short)0;
    }
}

// ---------------- lightweight grid barrier (co-resident grid only) ----------
// bar[0] = arrival counter, bar[32] = sense (separate cache lines).
// Cooperative launch guarantees all NB_ WGs are resident -> no deadlock.

__device__ __forceinline__ void gbar(int* bar, int it) {
    __syncthreads();
    if (threadIdx.x == 0) {
        __threadfence();                         // release (flush XCD L2)
        int a = __hip_atomic_fetch_add(&bar[0], 1, __ATOMIC_ACQ_REL,
                                       __HIP_MEMORY_SCOPE_AGENT);
        if (a == NB_ - 1) {
            __hip_atomic_store(&bar[0], 0, __ATOMIC_RELAXED,
                               __HIP_MEMORY_SCOPE_AGENT);
            __hip_atomic_store(&bar[32], it + 1, __ATOMIC_RELEASE,
                               __HIP_MEMORY_SCOPE_AGENT);
        } else {
            while (__hip_atomic_load(&bar[32], __ATOMIC_ACQUIRE,
                                     __HIP_MEMORY_SCOPE_AGENT) <= it)
                __builtin_amdgcn_s_sleep(2);
        }
        __threadfence();                         // acquire (invalidate L1/L2)
    }
    __syncthreads();
}

// ---------------- common pieces ---------------------------------------------

#define MFMA8(A, Bv)                                                         \
    do {                                                                     \
        _Pragma("unroll")                                                    \
        for (int mt = 0; mt < 2; ++mt)                                       \
            _Pragma("unroll")                                                \
            for (int nt = 0; nt < 4; ++nt)                                   \
                acc[mt][nt] = __builtin_amdgcn_mfma_f32_16x16x32_bf16(       \
                                  A[mt], Bv[nt], acc[mt][nt], 0, 0, 0);      \
    } while (0)

// two-phase 8->4->1 reduce + bias + activation + store epilogue.
// C/D layout: col(b within 16-tile)=lane&15, row(i)=quad*4+q.
#define REDUCE_EPILOGUE(LASTF)                                               \
    do {                                                                     \
        if (wv >= 4) {                                                       \
            _Pragma("unroll")                                                \
            for (int mt = 0; mt < 2; ++mt)                                   \
                _Pragma("unroll")                                            \
                for (int nt = 0; nt < 4; ++nt)                               \
                    _Pragma("unroll")                                        \
                    for (int q2 = 0; q2 < 4; ++q2)                           \
                        s_red[wv - 4][nt * 16 + half][mt * 16 + quad * 4 + q2] = \
                            acc[mt][nt][q2];                                 \
        }                                                                    \
        __syncthreads();                                                     \
        if (wv < 4) {                                                        \
            _Pragma("unroll")                                                \
            for (int mt = 0; mt < 2; ++mt)                                   \
                _Pragma("unroll")                                            \
                for (int nt = 0; nt < 4; ++nt)                               \
                    _Pragma("unroll")                                        \
                    for (int q2 = 0; q2 < 4; ++q2)                           \
                        s_red[wv][nt * 16 + half][mt * 16 + quad * 4 + q2] += \
                            acc[mt][nt][q2];                                 \
        }                                                                    \
        __syncthreads();                                                     \
        const int b  = tid >> 3;                                             \
        const int i0 = (tid & 7) * 4;                                        \
        const float4 bv = *(const float4*)&bias[r * 32 + i0];                \
        float v[4] = {bv.x, bv.y, bv.z, bv.w};                               \
        _Pragma("unroll")                                                    \
        for (int w = 0; w < 4; ++w)                                          \
            _Pragma("unroll")                                                \
            for (int k = 0; k < 4; ++k)                                      \
                v[k] += s_red[w][b][i0 + k];                                 \
        if (LASTF) {                                                         \
            float4 o;                                                        \
            o.x = 1.0f / (1.0f + __expf(-v[0]));                             \
            o.y = 1.0f / (1.0f + __expf(-v[1]));                             \
            o.z = 1.0f / (1.0f + __expf(-v[2]));                             \
            o.w = 1.0f / (1.0f + __expf(-v[3]));                             \
            *(float4*)&out[(size_t)b * N_OUT_ +                              \
                           (r - (NB_ - N_OUT_ / 32)) * 32 + i0] = o;         \
        } else {                                                             \
            union { unsigned short s[4]; uint2 u; } o;                       \
            _Pragma("unroll")                                                \
            for (int k = 0; k < 4; ++k)                                      \
                o.s[k] = f2bf(1.0f / (1.0f + __expf(-v[k])));                \
            *(uint2*)&xout[((size_t)r * 64 + b) * 32 + i0] = o.u;            \
        }                                                                    \
    } while (0)

// readlane depth-2 stage load (steps 1..7): weight stride pure, x-offset from
// lane-held register. Clamped index: redundant re-load of last pair is an L1 hit.
#define LDST2(A, Bv, t)                                                      \
    do {                                                                     \
        int tt = ((t) < mv - 1) ? (t) : (mv - 1);                            \
        const unsigned short* wp = wbase + (size_t)tt * 1024;                \
        A[0] = ldfrag(wp);                                                   \
        A[1] = ldfrag(wp + 512);                                             \
        int xo = __builtin_amdgcn_readlane(xoff, tt);                        \
        const unsigned short* xp = x + xo + off16;                           \
        Bv[0] = ldfrag(xp);                                                  \
        Bv[1] = ldfrag(xp + 512);                                            \
        Bv[2] = ldfrag(xp + 1024);                                           \
        Bv[3] = ldfrag(xp + 1536);                                           \
    } while (0)

// ---------------- ALL 8 steps, persistent cooperative + custom barrier ------

__global__ __launch_bounds__(512, 4) void fused2_k(
        const unsigned short* __restrict__ xa,   // [NB][64][32] (step-even src)
        unsigned short* __restrict__ xb_,        // [NB][64][32] (step-even dst)
        float* __restrict__ out,                 // [B][N_OUT] f32
        const unsigned short* __restrict__ wb,   // [NNZ][32][32] bf16, permuted
        const float* __restrict__ bias,
        const int2* __restrict__ pair2,          // row-sorted (n, c)
        const int* __restrict__ ptr,
        int* __restrict__ bar) {
    __shared__ int2  s_pairs[8][64];             // step-0 filter only, 4 KB
    __shared__ float s_red[4][64][33];           // 33.8 KB

    const int r    = blockIdx.x;
    const int tid  = threadIdx.x;
    const int wv   = tid >> 6;                   // 0..7
    const int lane = tid & 63;
    const int half = lane & 15;
    const int quad = lane >> 4;

    const int beg = ptr[r], cnt = ptr[r + 1] - beg;
    const int c0 = __builtin_amdgcn_readfirstlane(beg + (cnt * wv) / 8);
    const int mv = __builtin_amdgcn_readfirstlane(beg + (cnt * (wv + 1)) / 8 - c0);

    // lane j holds (sorted position, col) of pair j; fetched once, reused 8x
    int pcol = 0;
    if (lane < mv) pcol = pair2[c0 + lane].y;
    const int xoff = pcol * 2048;                // x slab offset in shorts

    const int off16 = half * 32 + quad * 8;
    const unsigned short* wbase = wb + (size_t)c0 * 1024 + off16;

    // ---- step 0: only cols < 32 are nonzero (filtered, tiny work) ----
    {
        const unsigned short* x = xa;
        unsigned short* xout = xb_;
        bool valid = (lane < mv) && (pcol < N_IN_ / 32);
        unsigned long long mask = __ballot(valid);
        if (valid) {
            int pos = __popcll(mask & ((1ull << lane) - 1ull));
            s_pairs[wv][pos] = make_int2(c0 + lane, pcol);
        }
        const int m0 = __popcll(mask);

        f32x4 acc[2][4] = {};
        bf16x8 A0[2], B0[4], A1[2], B1[4];
        #define LDP0(A, Bv, p)                                               \
            do {                                                             \
                const unsigned short* wp = wb + (size_t)(p).x * 1024 + off16;\
                A[0] = ldfrag(wp);                                           \
                A[1] = ldfrag(wp + 512);                                     \
                const unsigned short* xp = x + (size_t)(p).y * 2048 + off16; \
                Bv[0] = ldfrag(xp);                                          \
                Bv[1] = ldfrag(xp + 512);                                    \
                Bv[2] = ldfrag(xp + 1024);                                   \
                Bv[3] = ldfrag(xp + 1536);                                   \
            } while (0)
        if (m0 > 0) { int2 p = s_pairs[wv][0]; LDP0(A0, B0, p); }
        int j = 0;
        while (j + 2 <= m0) {
            { int2 p = s_pairs[wv][j + 1]; LDP0(A1, B1, p); }
            MFMA8(A0, B0);
            if (j + 2 < m0) { int2 p = s_pairs[wv][j + 2]; LDP0(A0, B0, p); }
            MFMA8(A1, B1);
            j += 2;
        }
        if (j < m0) MFMA8(A0, B0);
        #undef LDP0

        REDUCE_EPILOGUE(false);
    }
    gbar(bar, 0);

    // ---- steps 1..7: full rows, readlane depth-2 pipeline ----
    for (int step = 1; step < 8; ++step) {
        const bool last = (step == 7);
        if (!last || r >= NB_ - N_OUT_ / 32) {
            const unsigned short* x = (step & 1) ? xb_ : xa;
            unsigned short* xout = (step & 1) ? const_cast<unsigned short*>(xa) : xb_;

            f32x4 acc[2][4] = {};
            bf16x8 A0[2], B0[4], A1[2], B1[4];

            if (mv > 0) {
                LDST2(A0, B0, 0);
                LDST2(A1, B1, 1);
                int j = 0;
                while (j + 2 < mv) {
                    MFMA8(A0, B0); LDST2(A0, B0, j + 2);
                    MFMA8(A1, B1); LDST2(A1, B1, j + 3);
                    j += 2;
                }
                MFMA8(A0, B0);
                if (mv - j > 1) MFMA8(A1, B1);
            }

            REDUCE_EPILOGUE(last);
        }
        if (step < 7) gbar(bar, step);
    }
}

// ---------------- fallback: separate launches (round-5 proven path) ---------

template <bool LAST>
__global__ __launch_bounds__(512, 4) void rowfull_k(
        const unsigned short* __restrict__ x,
        unsigned short* __restrict__ xout,
        float* __restrict__ out,
        const unsigned short* __restrict__ wb,
        const float* __restrict__ bias,
        const int2* __restrict__ pair2,
        const int* __restrict__ ptr,
        int row_base) {
    __shared__ float s_red[4][64][33];

    const int r    = blockIdx.x + row_base;
    const int tid  = threadIdx.x;
    const int wv   = tid >> 6;
    const int lane = tid & 63;
    const int half = lane & 15;
    const int quad = lane >> 4;

    const int beg = ptr[r], cnt = ptr[r + 1] - beg;
    const int c0 = __builtin_amdgcn_readfirstlane(beg + (cnt * wv) / 8);
    const int mv = __builtin_amdgcn_readfirstlane(beg + (cnt * (wv + 1)) / 8 - c0);

    int xoff = 0;
    if (lane < mv) xoff = pair2[c0 + lane].y * 2048;

    const int off16 = half * 32 + quad * 8;
    const unsigned short* wbase = wb + (size_t)c0 * 1024 + off16;

    f32x4 acc[2][4] = {};
    bf16x8 A0[2], B0[4], A1[2], B1[4];

    if (mv > 0) {
        LDST2(A0, B0, 0);
        LDST2(A1, B1, 1);
        int j = 0;
        while (j + 2 < mv) {
            MFMA8(A0, B0); LDST2(A0, B0, j + 2);
            MFMA8(A1, B1); LDST2(A1, B1, j + 3);
            j += 2;
        }
        MFMA8(A0, B0);
        if (mv - j > 1) MFMA8(A1, B1);
    }

    REDUCE_EPILOGUE(LAST);
}

__global__ __launch_bounds__(512, 4) void rowstep0_k(
        const unsigned short* __restrict__ x,
        unsigned short* __restrict__ xout,
        const unsigned short* __restrict__ wb,
        const float* __restrict__ bias,
        const int2* __restrict__ pair2,
        const int* __restrict__ ptr) {
    __shared__ int2  s_pairs[8][64];
    __shared__ float s_red[4][64][33];
    float* __restrict__ out = nullptr;

    const int r    = blockIdx.x;
    const int tid  = threadIdx.x;
    const int wv   = tid >> 6;
    const int lane = tid & 63;
    const int half = lane & 15;
    const int quad = lane >> 4;

    const int beg = ptr[r], cnt = ptr[r + 1] - beg;
    const int c0 = beg + (cnt * wv) / 8;
    const int m  = beg + (cnt * (wv + 1)) / 8 - c0;

    int2 pc = make_int2(0, 0);
    bool valid = (lane < m);
    if (valid) {
        int c = pair2[c0 + lane].y;
        pc = make_int2(c0 + lane, c);
        valid = (c < N_IN_ / 32);
    }
    unsigned long long mask = __ballot(valid);
    if (valid) {
        int pos = __popcll(mask & ((1ull << lane) - 1ull));
        s_pairs[wv][pos] = pc;
    }
    const int mv = __popcll(mask);

    const int off16 = half * 32 + quad * 8;

    f32x4 acc[2][4] = {};
    bf16x8 A0[2], B0[4], A1[2], B1[4];

    #define LDP0(A, Bv, p)                                                   \
        do {                                                                 \
            const unsigned short* wp = wb + (size_t)(p).x * 1024 + off16;    \
            A[0] = ldfrag(wp);                                               \
            A[1] = ldfrag(wp + 512);                                         \
            const unsigned short* xp = x + (size_t)(p).y * 2048 + off16;     \
            Bv[0] = ldfrag(xp);                                              \
            Bv[1] = ldfrag(xp + 512);                                        \
            Bv[2] = ldfrag(xp + 1024);                                       \
            Bv[3] = ldfrag(xp + 1536);                                       \
        } while (0)
    if (mv > 0) { int2 p = s_pairs[wv][0]; LDP0(A0, B0, p); }
    int j = 0;
    while (j + 2 <= mv) {
        { int2 p = s_pairs[wv][j + 1]; LDP0(A1, B1, p); }
        MFMA8(A0, B0);
        if (j + 2 < mv) { int2 p = s_pairs[wv][j + 2]; LDP0(A0, B0, p); }
        MFMA8(A1, B1);
        j += 2;
    }
    if (j < mv) MFMA8(A0, B0);
    #undef LDP0

    REDUCE_EPILOGUE(false);
}

// ---------------- launcher --------------------------------------------------

extern "C" void kernel_launch(void* const* d_in, const int* in_sizes, int n_in,
                              void* d_out, int out_size, void* d_ws, size_t ws_size,
                              hipStream_t stream) {
    const float* inp    = (const float*)d_in[0];
    const float* blocks = (const float*)d_in[1];
    const float* bias   = (const float*)d_in[2];
    const int*   rows   = (const int*)d_in[3];
    const int*   cols   = (const int*)d_in[4];
    float*       out    = (float*)d_out;

    char* ws = (char*)d_ws;
    unsigned short* wbf = (unsigned short*)ws;                       // 53.69 MB
    unsigned short* x0  = (unsigned short*)(ws + 53686272u);         // 2 MB
    unsigned short* x1  = (unsigned short*)(ws + 53686272u + 2097152u);
    char*  idxbase      = ws + 53686272u + 2u * 2097152u;
    int*   rowptr = (int*)(idxbase);                                  // 513 ints
    int2*  pair2  = (int2*)(idxbase + 8192);                          // NNZ int2
    int*   bar    = (int*)(idxbase + 262144);                         // barrier

    // 1) index build + barrier zero (single WG)
    index_k<<<1, 1024, 0, stream>>>(rows, cols, rowptr, pair2, bar);

    // 2) weights -> bf16 permuted + blocked-x init (one dispatch)
    prep_k<<<NNZ_ + (B_ * H_) / 256, 256, 0, stream>>>(blocks, wbf, pair2, inp, x0);

    // 3) all 8 steps, persistent cooperative kernel with custom grid barrier
    void* kargs[] = { (void*)&x0, (void*)&x1, (void*)&out, (void*)&wbf,
                      (void*)&bias, (void*)&pair2, (void*)&rowptr, (void*)&bar };
    hipError_t ce = hipLaunchCooperativeKernel(
        reinterpret_cast<void*>(fused2_k), dim3(NB_), dim3(512), kargs, 0, stream);

    if (ce != hipSuccess) {
        (void)hipGetLastError();   // clear sticky error; separate-launch fallback
        unsigned short* cur = x0;
        unsigned short* nxt = x1;
        rowstep0_k<<<NB_, 512, 0, stream>>>(cur, nxt, wbf, bias, pair2, rowptr);
        { unsigned short* t = cur; cur = nxt; nxt = t; }
        for (int s = 1; s < 7; ++s) {
            rowfull_k<false><<<NB_, 512, 0, stream>>>(cur, nxt, nullptr, wbf, bias,
                                                      pair2, rowptr, 0);
            unsigned short* t = cur; cur = nxt; nxt = t;
        }
        rowfull_k<true><<<N_OUT_ / 32, 512, 0, stream>>>(cur, nullptr, out, wbf,
                                                         bias, pair2, rowptr,
                                                         NB_ - N_OUT_ / 32);
    }
}

// Round 7
// 314.669 us; speedup vs baseline: 2.4318x; 2.4318x over previous
//
#include <hip/hip_runtime.h>
#include <stdint.h>

#define B_     64
#define H_     16384
#define NB_    512
#define NNZ_   26214
#define N_IN_  1024
#define N_OUT_ 1024
#define NCONV_ ((NNZ_ + 3) / 4)     // conv WGs (4 weight blocks per 1024-thr WG)
#define NINIT_ ((B_ * H_) / 1024)   // init WGs

typedef __attribute__((ext_vector_type(8))) short    bf16x8;
typedef __attribute__((ext_vector_type(4))) float    f32x4;
typedef __attribute__((ext_vector_type(4))) unsigned int u32x4;

__device__ __forceinline__ unsigned short f2bf(float f) {
    union { unsigned int i; float f; } v; v.f = f;
    unsigned int x = v.i;
    return (unsigned short)((x + 0x7fffu + ((x >> 16) & 1u)) >> 16);
}

__device__ __forceinline__ bf16x8 ldfrag(const unsigned short* p) {
    union { u32x4 u; bf16x8 b; } cv;
    cv.u = *(const u32x4*)p;     // 16B aligned by construction
    return cv.b;
}

// ---------------- ONE prep dispatch: index build + w->bf16 + x init ---------
// block 0          : hist+scan+scatter (LDS, 1024 thr) -> rowptr, pair2
// blocks 1..NCONV_ : weights f32->bf16 RNE, 4 blocks/WG (NO permutation:
//                    wbf[n] = bf16(blocks[n]) -- independent of index build)
// blocks > NCONV_  : blocked x[c][b][j] bf16 init from inp (zero-padded)

__global__ __launch_bounds__(1024) void prepidx_k(
        const int* __restrict__ rows, const int* __restrict__ cols,
        int* __restrict__ rowptr, int2* __restrict__ pair2,
        const float* __restrict__ w, unsigned short* __restrict__ wb,
        const float* __restrict__ inp, unsigned short* __restrict__ xb) {
    const int bb = blockIdx.x;
    const int t  = threadIdx.x;

    if (bb == 0) {
        __shared__ int s_cnt[NB_];
        __shared__ int s_off[NB_];
        if (t < NB_) s_cnt[t] = 0;
        __syncthreads();
        for (int n = t; n < NNZ_; n += 1024)
            atomicAdd(&s_cnt[rows[n]], 1);
        __syncthreads();
        for (int off = 1; off < NB_; off <<= 1) {
            int v = 0;
            if (t < NB_ && t >= off) v = s_cnt[t - off];
            __syncthreads();
            if (t < NB_) s_cnt[t] += v;
            __syncthreads();
        }
        if (t == 0) rowptr[0] = 0;
        if (t < NB_) {
            rowptr[t + 1] = s_cnt[t];
            s_off[t] = (t == 0) ? 0 : s_cnt[t - 1];
        }
        __syncthreads();
        for (int n = t; n < NNZ_; n += 1024) {
            int r = rows[n];
            int pos = atomicAdd(&s_off[r], 1);
            pair2[pos] = make_int2(n, cols[n]);
        }
    } else if (bb <= NCONV_) {
        int n = (bb - 1) * 4 + (t >> 8);         // weight block
        if (n < NNZ_) {
            int q = t & 255;                     // float4 slot within block
            f32x4 v = __builtin_nontemporal_load(
                          (const f32x4*)(w + (size_t)n * 1024) + q);
            union { unsigned short s[4]; uint2 d; } o;
            o.s[0] = f2bf(v[0]); o.s[1] = f2bf(v[1]);
            o.s[2] = f2bf(v[2]); o.s[3] = f2bf(v[3]);
            ((uint2*)(wb + (size_t)n * 1024))[q] = o.d;
        }
    } else {
        int idx = (bb - NCONV_ - 1) * 1024 + t;  // 0 .. B*H-1 blocked linear
        int c = idx >> 11;                       // 64*32 elems per c-slab
        int b = (idx >> 5) & 63;
        int j = idx & 31;
        int h = c * 32 + j;
        xb[idx] = (h < N_IN_) ? f2bf(inp[b * N_IN_ + h]) : (unsigned short)0;
    }
}

// ---------------- common pieces ---------------------------------------------

#define MFMA8(A, Bv)                                                         \
    do {                                                                     \
        _Pragma("unroll")                                                    \
        for (int mt = 0; mt < 2; ++mt)                                       \
            _Pragma("unroll")                                                \
            for (int nt = 0; nt < 4; ++nt)                                   \
                acc[mt][nt] = __builtin_amdgcn_mfma_f32_16x16x32_bf16(       \
                                  A[mt], Bv[nt], acc[mt][nt], 0, 0, 0);      \
    } while (0)

// two-phase 8->4->1 reduce + bias + activation + store epilogue.
// C/D layout: col(b within 16-tile)=lane&15, row(i)=quad*4+q.
#define REDUCE_EPILOGUE(LASTF)                                               \
    do {                                                                     \
        if (wv >= 4) {                                                       \
            _Pragma("unroll")                                                \
            for (int mt = 0; mt < 2; ++mt)                                   \
                _Pragma("unroll")                                            \
                for (int nt = 0; nt < 4; ++nt)                               \
                    _Pragma("unroll")                                        \
                    for (int q2 = 0; q2 < 4; ++q2)                           \
                        s_red[wv - 4][nt * 16 + half][mt * 16 + quad * 4 + q2] = \
                            acc[mt][nt][q2];                                 \
        }                                                                    \
        __syncthreads();                                                     \
        if (wv < 4) {                                                        \
            _Pragma("unroll")                                                \
            for (int mt = 0; mt < 2; ++mt)                                   \
                _Pragma("unroll")                                            \
                for (int nt = 0; nt < 4; ++nt)                               \
                    _Pragma("unroll")                                        \
                    for (int q2 = 0; q2 < 4; ++q2)                           \
                        s_red[wv][nt * 16 + half][mt * 16 + quad * 4 + q2] += \
                            acc[mt][nt][q2];                                 \
        }                                                                    \
        __syncthreads();                                                     \
        const int b  = tid >> 3;                                             \
        const int i0 = (tid & 7) * 4;                                        \
        const float4 bv = *(const float4*)&bias[r * 32 + i0];                \
        float v[4] = {bv.x, bv.y, bv.z, bv.w};                               \
        _Pragma("unroll")                                                    \
        for (int w = 0; w < 4; ++w)                                          \
            _Pragma("unroll")                                                \
            for (int k = 0; k < 4; ++k)                                      \
                v[k] += s_red[w][b][i0 + k];                                 \
        if (LASTF) {                                                         \
            float4 o;                                                        \
            o.x = 1.0f / (1.0f + __expf(-v[0]));                             \
            o.y = 1.0f / (1.0f + __expf(-v[1]));                             \
            o.z = 1.0f / (1.0f + __expf(-v[2]));                             \
            o.w = 1.0f / (1.0f + __expf(-v[3]));                             \
            *(float4*)&out[(size_t)b * N_OUT_ +                              \
                           (r - (NB_ - N_OUT_ / 32)) * 32 + i0] = o;         \
        } else {                                                             \
            union { unsigned short s[4]; uint2 u; } o;                       \
            _Pragma("unroll")                                                \
            for (int k = 0; k < 4; ++k)                                      \
                o.s[k] = f2bf(1.0f / (1.0f + __expf(-v[k])));                \
            *(uint2*)&xout[((size_t)r * 64 + b) * 32 + i0] = o.u;            \
        }                                                                    \
    } while (0)

// depth-2 stage load (full steps): lane j holds pair j's (weight idx, x off);
// both readlane'd with SGPR-uniform index (clamped -> redundant L1 re-hit).
#define LDST2(A, Bv, t)                                                      \
    do {                                                                     \
        int tt = ((t) < mv - 1) ? (t) : (mv - 1);                            \
        int nn = __builtin_amdgcn_readlane(nidx, tt);                        \
        const unsigned short* wp = wb + (size_t)nn * 1024 + off16;           \
        A[0] = ldfrag(wp);                                                   \
        A[1] = ldfrag(wp + 512);                                             \
        int xo = __builtin_amdgcn_readlane(xoff, tt);                        \
        const unsigned short* xp = x + xo + off16;                           \
        Bv[0] = ldfrag(xp);                                                  \
        Bv[1] = ldfrag(xp + 512);                                            \
        Bv[2] = ldfrag(xp + 1024);                                           \
        Bv[3] = ldfrag(xp + 1536);                                           \
    } while (0)

// ---------------- full step: one WG (8 waves) per row -----------------------

template <bool LAST>
__global__ __launch_bounds__(512, 4) void rowfull_k(
        const unsigned short* __restrict__ x,    // [NB][64][32] bf16 blocked
        unsigned short* __restrict__ xout,       // [NB][64][32] bf16 blocked
        float* __restrict__ out,                 // [B][N_OUT] f32 (LAST only)
        const unsigned short* __restrict__ wb,   // [NNZ][32][32] bf16 (natural)
        const float* __restrict__ bias,
        const int2* __restrict__ pair2,          // row-sorted (n, c)
        const int* __restrict__ ptr,
        int row_base) {
    __shared__ float s_red[4][64][33];           // 33.8 KB

    const int r    = blockIdx.x + row_base;
    const int tid  = threadIdx.x;
    const int wv   = tid >> 6;                   // 0..7
    const int lane = tid & 63;
    const int half = lane & 15;
    const int quad = lane >> 4;

    const int beg = ptr[r], cnt = ptr[r + 1] - beg;
    const int c0 = __builtin_amdgcn_readfirstlane(beg + (cnt * wv) / 8);
    const int mv = __builtin_amdgcn_readfirstlane(beg + (cnt * (wv + 1)) / 8 - c0);

    int nidx = 0, xoff = 0;
    if (lane < mv) {
        int2 p = pair2[c0 + lane];
        nidx = p.x;
        xoff = p.y * 2048;                       // x slab offset in shorts
    }

    const int off16 = half * 32 + quad * 8;

    f32x4 acc[2][4] = {};
    bf16x8 A0[2], B0[4], A1[2], B1[4];

    if (mv > 0) {
        LDST2(A0, B0, 0);
        LDST2(A1, B1, 1);
        int j = 0;
        while (j + 2 < mv) {
            MFMA8(A0, B0); LDST2(A0, B0, j + 2);
            MFMA8(A1, B1); LDST2(A1, B1, j + 3);
            j += 2;
        }
        MFMA8(A0, B0);
        if (mv - j > 1) MFMA8(A1, B1);
    }

    REDUCE_EPILOGUE(LAST);
}

// ---------------- step 0: column filter (c < 32), tiny work -----------------

__global__ __launch_bounds__(512, 4) void rowstep0_k(
        const unsigned short* __restrict__ x,
        unsigned short* __restrict__ xout,
        const unsigned short* __restrict__ wb,
        const float* __restrict__ bias,
        const int2* __restrict__ pair2,
        const int* __restrict__ ptr) {
    __shared__ int2  s_pairs[8][64];
    __shared__ float s_red[4][64][33];
    float* __restrict__ out = nullptr;           // unused (never LAST)

    const int r    = blockIdx.x;
    const int tid  = threadIdx.x;
    const int wv   = tid >> 6;
    const int lane = tid & 63;
    const int half = lane & 15;
    const int quad = lane >> 4;

    const int beg = ptr[r], cnt = ptr[r + 1] - beg;
    const int c0 = beg + (cnt * wv) / 8;
    const int m  = beg + (cnt * (wv + 1)) / 8 - c0;

    int2 pc = make_int2(0, 0);
    bool valid = (lane < m);
    if (valid) {
        int2 p = pair2[c0 + lane];
        pc = p;                                  // (n, c)
        valid = (p.y < N_IN_ / 32);
    }
    unsigned long long mask = __ballot(valid);
    if (valid) {
        int pos = __popcll(mask & ((1ull << lane) - 1ull));
        s_pairs[wv][pos] = pc;                   // intra-wave only: no barrier
    }
    const int mv = __popcll(mask);

    const int off16 = half * 32 + quad * 8;

    f32x4 acc[2][4] = {};
    bf16x8 A0[2], B0[4], A1[2], B1[4];

    #define LDP0(A, Bv, p)                                                   \
        do {                                                                 \
            const unsigned short* wp = wb + (size_t)(p).x * 1024 + off16;    \
            A[0] = ldfrag(wp);                                               \
            A[1] = ldfrag(wp + 512);                                         \
            const unsigned short* xp = x + (size_t)(p).y * 2048 + off16;     \
            Bv[0] = ldfrag(xp);                                              \
            Bv[1] = ldfrag(xp + 512);                                        \
            Bv[2] = ldfrag(xp + 1024);                                       \
            Bv[3] = ldfrag(xp + 1536);                                       \
        } while (0)
    if (mv > 0) { int2 p = s_pairs[wv][0]; LDP0(A0, B0, p); }
    int j = 0;
    while (j + 2 <= mv) {
        { int2 p = s_pairs[wv][j + 1]; LDP0(A1, B1, p); }
        MFMA8(A0, B0);
        if (j + 2 < mv) { int2 p = s_pairs[wv][j + 2]; LDP0(A0, B0, p); }
        MFMA8(A1, B1);
        j += 2;
    }
    if (j < mv) MFMA8(A0, B0);
    #undef LDP0

    REDUCE_EPILOGUE(false);
}

// ---------------- launcher: 9 dispatches total ------------------------------

extern "C" void kernel_launch(void* const* d_in, const int* in_sizes, int n_in,
                              void* d_out, int out_size, void* d_ws, size_t ws_size,
                              hipStream_t stream) {
    const float* inp    = (const float*)d_in[0];
    const float* blocks = (const float*)d_in[1];
    const float* bias   = (const float*)d_in[2];
    const int*   rows   = (const int*)d_in[3];
    const int*   cols   = (const int*)d_in[4];
    float*       out    = (float*)d_out;

    char* ws = (char*)d_ws;
    unsigned short* wbf = (unsigned short*)ws;                       // 53.69 MB
    unsigned short* x0  = (unsigned short*)(ws + 53686272u);         // 2 MB
    unsigned short* x1  = (unsigned short*)(ws + 53686272u + 2097152u);
    char*  idxbase      = ws + 53686272u + 2u * 2097152u;
    int*   rowptr = (int*)(idxbase);                                  // 513 ints
    int2*  pair2  = (int2*)(idxbase + 8192);                          // NNZ int2

    // 1) index build + weight convert + x init, ONE dispatch
    prepidx_k<<<1 + NCONV_ + NINIT_, 1024, 0, stream>>>(
        rows, cols, rowptr, pair2, blocks, wbf, inp, x0);

    unsigned short* cur = x0;
    unsigned short* nxt = x1;
    // 2) step 0: input nonzero only in first 32 col-blocks (filtered path)
    rowstep0_k<<<NB_, 512, 0, stream>>>(cur, nxt, wbf, bias, pair2, rowptr);
    { unsigned short* t = cur; cur = nxt; nxt = t; }
    // 3-8) steps 1..6: full rows
    for (int s = 1; s < 7; ++s) {
        rowfull_k<false><<<NB_, 512, 0, stream>>>(cur, nxt, nullptr, wbf, bias,
                                                  pair2, rowptr, 0);
        unsigned short* t = cur; cur = nxt; nxt = t;
    }
    // 9) step 7: only rows 480..511 feed the output; fused sigmoid -> f32 out
    rowfull_k<true><<<N_OUT_ / 32, 512, 0, stream>>>(cur, nullptr, out, wbf, bias,
                                                     pair2, rowptr,
                                                     NB_ - N_OUT_ / 32);
}